// Round 6
// baseline (411.850 us; speedup 1.0000x reference)
//
#include <hip/hip_runtime.h>
#include <math.h>

// Problem constants (fixed by the reference)
constexpr int NG    = 128;          // graphs
constexpr int NP    = 1024;         // nodes per graph
constexpr int D     = 256;          // feature dim
constexpr int NTOT  = NG * NP;      // 131072 nodes
constexpr int EPG   = NP * 32;      // 32768 edges per graph (contiguous slice)
constexpr int ET    = NTOT * 32;    // 4194304 edges
constexpr int KK    = 820;          // kept per graph
constexpr int KQ    = KK / 4;       // 205 kept rows per quarter-block
constexpr int NKEEP = NG * KK;      // 104960 kept nodes
constexpr int EQ    = EPG / 4;      // 8192 edges per quarter-block

// Native clang vector type: __builtin_nontemporal_store rejects HIP float4
typedef float v4f __attribute__((ext_vector_type(4)));

// Output layout (flat float32, reference return order)
constexpr long long OUT_X     = 0;
constexpr long long OUT_EI0   = (long long)NKEEP * D;     // 26869760
constexpr long long OUT_EI1   = OUT_EI0 + ET;
constexpr long long OUT_MASK  = OUT_EI0 + 2LL * ET;
constexpr long long OUT_BATCH = OUT_MASK + ET;
constexpr long long OUT_PERM  = OUT_BATCH + NKEEP;        // total 39662592

// ---------------------------------------------------------------------------
// ONE kernel, 512 blocks x 1024 threads -> 2 blocks/CU (32 waves, 49 KB LDS),
// so two blocks in different phases overlap on each CU (the round-5 version
// had 1 block/CU = 50% occupancy cap and exposed every phase's latency).
// Blocks 4g..4g+3 each redundantly run graph g's prologue in LDS
// (h -> deg -> acc -> score -> bitonic top-k -> new_id; redundant compute is
// cheap: VALUBusy was 7%), then split the epilogue in quarters: block q
// writes gather rows [q*205, +205) and edge slice [q*8192, +8192).
// No grid sync, no global intermediates, no workspace.
__global__ __launch_bounds__(1024) void sagpool_fused(
        const float* __restrict__ x,   const float* __restrict__ W,
        const float* __restrict__ bptr,
        const int* __restrict__ rows,  const int* __restrict__ cols,
        float* __restrict__ out) {
    __shared__ float h_lds[NP];             // 4 KB; later aliased as kidx
    __shared__ unsigned long long sk[NP];   // 8 KB; cnt | ul, then sort buffer
    __shared__ float acc[NP];               // 4 KB; later aliased as kfac
    __shared__ float scl[NP];               // 4 KB; scores
    __shared__ int   nid[NP];               // 4 KB; new_id for this graph
    int*   cnt  = (int*)sk;                 // bytes [0, 4K)
    float* ul   = (float*)sk + NP;          // bytes [4K, 8K)
    int*   kidx = (int*)h_lds;              // h dead after score
    float* kfac = acc;                      // acc dead after score

    const int blk  = blockIdx.x;            // 0..511
    const int t    = threadIdx.x;           // 0..1023
    const int w    = t >> 6;                // wave 0..15
    const int lane = t & 63;
    const int g    = blk >> 2;
    const int q    = blk & 3;               // epilogue quarter

    cnt[t] = 0;
    nid[t] = -1;

    // -------- Phase A: h[r] = dot(x[g*NP+r,:], W) for ALL 1024 rows --------
    // wave w owns rows [w*64, w*64+64), 4 rows in flight per chunk.
    {
        float4 w4 = ((const float4*)W)[lane];
        const float4* xp = (const float4*)(x + (size_t)g * NP * D);
#pragma unroll
        for (int c = 0; c < 16; ++c) {
            const int r0 = w * 64 + c * 4;
            float4 a0 = xp[(r0 + 0) * 64 + lane];
            float4 a1 = xp[(r0 + 1) * 64 + lane];
            float4 a2 = xp[(r0 + 2) * 64 + lane];
            float4 a3 = xp[(r0 + 3) * 64 + lane];
            float s0 = a0.x * w4.x + a0.y * w4.y + a0.z * w4.z + a0.w * w4.w;
            float s1 = a1.x * w4.x + a1.y * w4.y + a1.z * w4.z + a1.w * w4.w;
            float s2 = a2.x * w4.x + a2.y * w4.y + a2.z * w4.z + a2.w * w4.w;
            float s3 = a3.x * w4.x + a3.y * w4.y + a3.z * w4.z + a3.w * w4.w;
#pragma unroll
            for (int off = 32; off > 0; off >>= 1) {
                s0 += __shfl_down(s0, off, 64);
                s1 += __shfl_down(s1, off, 64);
                s2 += __shfl_down(s2, off, 64);
                s3 += __shfl_down(s3, off, 64);
            }
            if (lane == 0) {
                h_lds[r0]     = s0; h_lds[r0 + 1] = s1;
                h_lds[r0 + 2] = s2; h_lds[r0 + 3] = s3;
            }
        }
    }
    __syncthreads();

    const int4* c4p = (const int4*)(cols + (size_t)g * EPG);
    const int4* r4p = (const int4*)(rows + (size_t)g * EPG);

    // -------- Phase B: degree over all 32768 edges (LDS atomics) -----------
#pragma unroll
    for (int i = t; i < EPG / 4; i += 1024) {        // 8 iters
        int4 c = c4p[i];
        atomicAdd(&cnt[c.x & (NP - 1)], 1);
        atomicAdd(&cnt[c.y & (NP - 1)], 1);
        atomicAdd(&cnt[c.z & (NP - 1)], 1);
        atomicAdd(&cnt[c.w & (NP - 1)], 1);
    }
    __syncthreads();

    const float hv = h_lds[t];
    const float di = rsqrtf((float)(1 + cnt[t]));    // self-loop included
    ul[t]  = di * hv;
    acc[t] = 0.0f;
    __syncthreads();

    // -------- Phase C: acc[c] += u[r] over all edges (LDS atomics) ---------
#pragma unroll
    for (int i = t; i < EPG / 4; i += 1024) {        // 8 iters
        int4 c = c4p[i];
        int4 r = r4p[i];
        atomicAdd(&acc[c.x & (NP - 1)], ul[r.x & (NP - 1)]);
        atomicAdd(&acc[c.y & (NP - 1)], ul[r.y & (NP - 1)]);
        atomicAdd(&acc[c.z & (NP - 1)], ul[r.z & (NP - 1)]);
        atomicAdd(&acc[c.w & (NP - 1)], ul[r.w & (NP - 1)]);
    }
    __syncthreads();

    // -------- Score + register bitonic full sort ---------------------------
    const float score = di * acc[t] + di * di * hv + bptr[0];
    scl[t] = score;

    // sortable key: ascending u64 == (descending score, ascending idx)
    unsigned int fu = __float_as_uint(score);
    unsigned int s  = (fu & 0x80000000u) ? ~fu : (fu | 0x80000000u);
    unsigned long long key = ((unsigned long long)(~s) << 32) | (unsigned int)t;
    // ul reads finished before last barrier; sk is free for sort stages.

    for (int k = 2; k <= NP; k <<= 1) {
        for (int j = k >> 1; j > 0; j >>= 1) {
            unsigned long long other;
            if (j < 64) {
                other = __shfl_xor(key, j, 64);
            } else {
                sk[t] = key;
                __syncthreads();
                other = sk[t ^ j];
                __syncthreads();
            }
            bool take_min = (((t & k) == 0) == ((t & j) == 0));
            bool omin = other < key;
            key = (take_min == omin) ? other : key;
        }
    }
    // sort's internal barriers ordered scl[] writes before the reads below

    // -------- Epilogue bookkeeping (LDS only; quarter-split outputs) -------
    if (t < KK) {
        int idx  = (int)(key & 0xFFFFFFFFull);
        nid[idx] = g * KK + t;                       // full new_id map in LDS
        if (t >= q * KQ && t < q * KQ + KQ) {        // this block's 205 rows
            const int l = t - q * KQ;
            kidx[l] = idx;
            kfac[l] = tanhf(scl[idx]);
            const int jj = g * KK + t;
            out[OUT_PERM + jj]  = (float)(g * NP + idx);
            out[OUT_BATCH + jj] = (float)g;          // contiguous graphs
        }
    }
    __syncthreads();

    // -------- Phase E1: gather x_new rows (205 per block) ------------------
    for (int l = w; l < KQ; l += 16) {               // 12-13 iters per wave
        const int   ni = kidx[l];
        const float f  = kfac[l];
        float4 v = ((const float4*)(x + ((size_t)(g * NP + ni)) * D))[lane];
        v4f o;
        o.x = v.x * f; o.y = v.y * f; o.z = v.z * f; o.w = v.w * f;
        const size_t j = (size_t)g * KK + q * KQ + l;
        __builtin_nontemporal_store(o, &((v4f*)(out + OUT_X + j * D))[lane]);
    }

    // -------- Phase E2: edge remap (8192 edges per block) ------------------
    {
        const size_t eoff = (size_t)g * EPG + (size_t)q * EQ;
        const int4* r4 = (const int4*)(rows + eoff);
        const int4* c4 = (const int4*)(cols + eoff);
        v4f* orr = (v4f*)(out + OUT_EI0  + eoff);
        v4f* occ = (v4f*)(out + OUT_EI1  + eoff);
        v4f* omm = (v4f*)(out + OUT_MASK + eoff);
#pragma unroll
        for (int i = t; i < EQ / 4; i += 1024) {     // 2 iters
            int4 r = r4[i];
            int4 c = c4[i];
            v4f fr, fc, fm;
            {
                int nr = nid[r.x & (NP - 1)], nc = nid[c.x & (NP - 1)];
                bool m = (nr >= 0) && (nc >= 0);
                fr.x = m ? (float)nr : -1.0f; fc.x = m ? (float)nc : -1.0f; fm.x = m ? 1.0f : 0.0f;
            }
            {
                int nr = nid[r.y & (NP - 1)], nc = nid[c.y & (NP - 1)];
                bool m = (nr >= 0) && (nc >= 0);
                fr.y = m ? (float)nr : -1.0f; fc.y = m ? (float)nc : -1.0f; fm.y = m ? 1.0f : 0.0f;
            }
            {
                int nr = nid[r.z & (NP - 1)], nc = nid[c.z & (NP - 1)];
                bool m = (nr >= 0) && (nc >= 0);
                fr.z = m ? (float)nr : -1.0f; fc.z = m ? (float)nc : -1.0f; fm.z = m ? 1.0f : 0.0f;
            }
            {
                int nr = nid[r.w & (NP - 1)], nc = nid[c.w & (NP - 1)];
                bool m = (nr >= 0) && (nc >= 0);
                fr.w = m ? (float)nr : -1.0f; fc.w = m ? (float)nc : -1.0f; fm.w = m ? 1.0f : 0.0f;
            }
            __builtin_nontemporal_store(fr, &orr[i]);
            __builtin_nontemporal_store(fc, &occ[i]);
            __builtin_nontemporal_store(fm, &omm[i]);
        }
    }
}

extern "C" void kernel_launch(void* const* d_in, const int* in_sizes, int n_in,
                              void* d_out, int out_size, void* d_ws, size_t ws_size,
                              hipStream_t stream) {
    (void)in_sizes; (void)n_in; (void)out_size; (void)d_ws; (void)ws_size;

    const float* x  = (const float*)d_in[0];
    const int*   ei = (const int*)d_in[1];
    // d_in[2] (batch) unused: graphs are contiguous so batch[node] = node/NP
    const float* W  = (const float*)d_in[3];
    const float* b  = (const float*)d_in[4];
    float* out = (float*)d_out;

    const int* rows = ei;        // edge_index[0] = sources
    const int* cols = ei + ET;   // edge_index[1] = targets

    // Single dispatch; zero workspace, zero global intermediates.
    hipLaunchKernelGGL(sagpool_fused, dim3(4 * NG), dim3(1024), 0, stream,
                       x, W, b, rows, cols, out);
}

// Round 7
// 393.802 us; speedup vs baseline: 1.0458x; 1.0458x over previous
//
#include <hip/hip_runtime.h>
#include <math.h>

// Problem constants (fixed by the reference)
constexpr int NG    = 128;          // graphs
constexpr int NP    = 1024;         // nodes per graph
constexpr int D     = 256;          // feature dim
constexpr int NTOT  = NG * NP;      // 131072 nodes
constexpr int EPG   = NP * 32;      // 32768 edges per graph (contiguous slice)
constexpr int ET    = NTOT * 32;    // 4194304 edges
constexpr int KK    = 820;          // kept per graph
constexpr int KQ    = KK / 4;       // 205 kept rows per quarter-block
constexpr int NKEEP = NG * KK;      // 104960 kept nodes
constexpr int EQ    = EPG / 4;      // 8192 edges per quarter-block

// Native clang vector type: __builtin_nontemporal_store rejects HIP float4
typedef float v4f __attribute__((ext_vector_type(4)));

// Output layout (flat float32, reference return order)
constexpr long long OUT_X     = 0;
constexpr long long OUT_EI0   = (long long)NKEEP * D;     // 26869760
constexpr long long OUT_EI1   = OUT_EI0 + ET;
constexpr long long OUT_MASK  = OUT_EI0 + 2LL * ET;
constexpr long long OUT_BATCH = OUT_MASK + ET;
constexpr long long OUT_PERM  = OUT_BATCH + NKEEP;        // total 39662592

// ---------------------------------------------------------------------------
// ONE kernel, 512 blocks x 1024 threads, 2 blocks/CU (32 waves, 24.5 KB LDS).
// XCD-AWARE SWIZZLE (the round-6 fix): physical block p runs on XCD p%8, so
// map p -> (graph g, quarter q) with g%8 == p%8. All 4 redundant blocks of a
// graph are then co-resident on ONE XCD and share its L2: the graph's 1 MB x
// slice and 256 KB edge slices are fetched from HBM once per XCD instead of
// four times (round 6 measured FETCH 429 MB from cross-XCD redundancy;
// time tracked hbm_bytes at ~2.55 TB/s, so dedup is the lever).
// Per XCD: 16 graphs x 4 quarters = 64 blocks = 32 CUs x 2 -> all resident.
// Each block redundantly runs graph g's prologue in LDS (h -> deg -> acc ->
// score -> bitonic top-k -> new_id), then writes quarter q of the epilogue
// (205 gather rows + 8192 remapped edges). No grid sync, no workspace.
__global__ __launch_bounds__(1024) void sagpool_fused(
        const float* __restrict__ x,   const float* __restrict__ W,
        const float* __restrict__ bptr,
        const int* __restrict__ rows,  const int* __restrict__ cols,
        float* __restrict__ out) {
    __shared__ float h_lds[NP];             // 4 KB; later aliased as kidx
    __shared__ unsigned long long sk[NP];   // 8 KB; cnt | ul, then sort buffer
    __shared__ float acc[NP];               // 4 KB; later aliased as kfac
    __shared__ float scl[NP];               // 4 KB; scores
    __shared__ int   nid[NP];               // 4 KB; new_id for this graph
    int*   cnt  = (int*)sk;                 // bytes [0, 4K)
    float* ul   = (float*)sk + NP;          // bytes [4K, 8K)
    int*   kidx = (int*)h_lds;              // h dead after score
    float* kfac = acc;                      // acc dead after score

    const int p    = blockIdx.x;            // 0..511 (physical)
    const int t    = threadIdx.x;           // 0..1023
    const int w    = t >> 6;                // wave 0..15
    const int lane = t & 63;
    // XCD-aware logical mapping: xcd = p%8; all 4 blocks of graph g on xcd g%8
    const int xcd  = p & 7;
    const int slot = p >> 3;                // 0..63 within XCD
    const int g    = ((slot >> 2) << 3) | xcd;   // g % 8 == xcd
    const int q    = slot & 3;              // epilogue quarter

    cnt[t] = 0;
    nid[t] = -1;

    // -------- Phase A: h[r] = dot(x[g*NP+r,:], W) for ALL 1024 rows --------
    // wave w owns rows [w*64, w*64+64), 4 rows in flight per chunk.
    {
        float4 w4 = ((const float4*)W)[lane];
        const float4* xp = (const float4*)(x + (size_t)g * NP * D);
#pragma unroll
        for (int c = 0; c < 16; ++c) {
            const int r0 = w * 64 + c * 4;
            float4 a0 = xp[(r0 + 0) * 64 + lane];
            float4 a1 = xp[(r0 + 1) * 64 + lane];
            float4 a2 = xp[(r0 + 2) * 64 + lane];
            float4 a3 = xp[(r0 + 3) * 64 + lane];
            float s0 = a0.x * w4.x + a0.y * w4.y + a0.z * w4.z + a0.w * w4.w;
            float s1 = a1.x * w4.x + a1.y * w4.y + a1.z * w4.z + a1.w * w4.w;
            float s2 = a2.x * w4.x + a2.y * w4.y + a2.z * w4.z + a2.w * w4.w;
            float s3 = a3.x * w4.x + a3.y * w4.y + a3.z * w4.z + a3.w * w4.w;
#pragma unroll
            for (int off = 32; off > 0; off >>= 1) {
                s0 += __shfl_down(s0, off, 64);
                s1 += __shfl_down(s1, off, 64);
                s2 += __shfl_down(s2, off, 64);
                s3 += __shfl_down(s3, off, 64);
            }
            if (lane == 0) {
                h_lds[r0]     = s0; h_lds[r0 + 1] = s1;
                h_lds[r0 + 2] = s2; h_lds[r0 + 3] = s3;
            }
        }
    }
    __syncthreads();

    const int4* c4p = (const int4*)(cols + (size_t)g * EPG);
    const int4* r4p = (const int4*)(rows + (size_t)g * EPG);

    // -------- Phase B: degree over all 32768 edges (LDS atomics) -----------
#pragma unroll
    for (int i = t; i < EPG / 4; i += 1024) {        // 8 iters
        int4 c = c4p[i];
        atomicAdd(&cnt[c.x & (NP - 1)], 1);
        atomicAdd(&cnt[c.y & (NP - 1)], 1);
        atomicAdd(&cnt[c.z & (NP - 1)], 1);
        atomicAdd(&cnt[c.w & (NP - 1)], 1);
    }
    __syncthreads();

    const float hv = h_lds[t];
    const float di = rsqrtf((float)(1 + cnt[t]));    // self-loop included
    ul[t]  = di * hv;
    acc[t] = 0.0f;
    __syncthreads();

    // -------- Phase C: acc[c] += u[r] over all edges (LDS atomics) ---------
#pragma unroll
    for (int i = t; i < EPG / 4; i += 1024) {        // 8 iters
        int4 c = c4p[i];
        int4 r = r4p[i];
        atomicAdd(&acc[c.x & (NP - 1)], ul[r.x & (NP - 1)]);
        atomicAdd(&acc[c.y & (NP - 1)], ul[r.y & (NP - 1)]);
        atomicAdd(&acc[c.z & (NP - 1)], ul[r.z & (NP - 1)]);
        atomicAdd(&acc[c.w & (NP - 1)], ul[r.w & (NP - 1)]);
    }
    __syncthreads();

    // -------- Score + register bitonic full sort ---------------------------
    const float score = di * acc[t] + di * di * hv + bptr[0];
    scl[t] = score;

    // sortable key: ascending u64 == (descending score, ascending idx)
    unsigned int fu = __float_as_uint(score);
    unsigned int s  = (fu & 0x80000000u) ? ~fu : (fu | 0x80000000u);
    unsigned long long key = ((unsigned long long)(~s) << 32) | (unsigned int)t;
    // ul reads finished before last barrier; sk is free for sort stages.

    for (int k = 2; k <= NP; k <<= 1) {
        for (int j = k >> 1; j > 0; j >>= 1) {
            unsigned long long other;
            if (j < 64) {
                other = __shfl_xor(key, j, 64);
            } else {
                sk[t] = key;
                __syncthreads();
                other = sk[t ^ j];
                __syncthreads();
            }
            bool take_min = (((t & k) == 0) == ((t & j) == 0));
            bool omin = other < key;
            key = (take_min == omin) ? other : key;
        }
    }
    // sort's internal barriers ordered scl[] writes before the reads below

    // -------- Epilogue bookkeeping (LDS only; quarter-split outputs) -------
    if (t < KK) {
        int idx  = (int)(key & 0xFFFFFFFFull);
        nid[idx] = g * KK + t;                       // full new_id map in LDS
        if (t >= q * KQ && t < q * KQ + KQ) {        // this block's 205 rows
            const int l = t - q * KQ;
            kidx[l] = idx;
            kfac[l] = tanhf(scl[idx]);
            const int jj = g * KK + t;
            out[OUT_PERM + jj]  = (float)(g * NP + idx);
            out[OUT_BATCH + jj] = (float)g;          // contiguous graphs
        }
    }
    __syncthreads();

    // -------- Phase E1: gather x_new rows (205 per block) ------------------
    for (int l = w; l < KQ; l += 16) {               // 12-13 iters per wave
        const int   ni = kidx[l];
        const float f  = kfac[l];
        float4 v = ((const float4*)(x + ((size_t)(g * NP + ni)) * D))[lane];
        v4f o;
        o.x = v.x * f; o.y = v.y * f; o.z = v.z * f; o.w = v.w * f;
        const size_t j = (size_t)g * KK + q * KQ + l;
        __builtin_nontemporal_store(o, &((v4f*)(out + OUT_X + j * D))[lane]);
    }

    // -------- Phase E2: edge remap (8192 edges per block) ------------------
    {
        const size_t eoff = (size_t)g * EPG + (size_t)q * EQ;
        const int4* r4 = (const int4*)(rows + eoff);
        const int4* c4 = (const int4*)(cols + eoff);
        v4f* orr = (v4f*)(out + OUT_EI0  + eoff);
        v4f* occ = (v4f*)(out + OUT_EI1  + eoff);
        v4f* omm = (v4f*)(out + OUT_MASK + eoff);
#pragma unroll
        for (int i = t; i < EQ / 4; i += 1024) {     // 2 iters
            int4 r = r4[i];
            int4 c = c4[i];
            v4f fr, fc, fm;
            {
                int nr = nid[r.x & (NP - 1)], nc = nid[c.x & (NP - 1)];
                bool m = (nr >= 0) && (nc >= 0);
                fr.x = m ? (float)nr : -1.0f; fc.x = m ? (float)nc : -1.0f; fm.x = m ? 1.0f : 0.0f;
            }
            {
                int nr = nid[r.y & (NP - 1)], nc = nid[c.y & (NP - 1)];
                bool m = (nr >= 0) && (nc >= 0);
                fr.y = m ? (float)nr : -1.0f; fc.y = m ? (float)nc : -1.0f; fm.y = m ? 1.0f : 0.0f;
            }
            {
                int nr = nid[r.z & (NP - 1)], nc = nid[c.z & (NP - 1)];
                bool m = (nr >= 0) && (nc >= 0);
                fr.z = m ? (float)nr : -1.0f; fc.z = m ? (float)nc : -1.0f; fm.z = m ? 1.0f : 0.0f;
            }
            {
                int nr = nid[r.w & (NP - 1)], nc = nid[c.w & (NP - 1)];
                bool m = (nr >= 0) && (nc >= 0);
                fr.w = m ? (float)nr : -1.0f; fc.w = m ? (float)nc : -1.0f; fm.w = m ? 1.0f : 0.0f;
            }
            __builtin_nontemporal_store(fr, &orr[i]);
            __builtin_nontemporal_store(fc, &occ[i]);
            __builtin_nontemporal_store(fm, &omm[i]);
        }
    }
}

extern "C" void kernel_launch(void* const* d_in, const int* in_sizes, int n_in,
                              void* d_out, int out_size, void* d_ws, size_t ws_size,
                              hipStream_t stream) {
    (void)in_sizes; (void)n_in; (void)out_size; (void)d_ws; (void)ws_size;

    const float* x  = (const float*)d_in[0];
    const int*   ei = (const int*)d_in[1];
    // d_in[2] (batch) unused: graphs are contiguous so batch[node] = node/NP
    const float* W  = (const float*)d_in[3];
    const float* b  = (const float*)d_in[4];
    float* out = (float*)d_out;

    const int* rows = ei;        // edge_index[0] = sources
    const int* cols = ei + ET;   // edge_index[1] = targets

    // Single dispatch; zero workspace, zero global intermediates.
    hipLaunchKernelGGL(sagpool_fused, dim3(4 * NG), dim3(1024), 0, stream,
                       x, W, b, rows, cols, out);
}

// Round 8
// 353.964 us; speedup vs baseline: 1.1635x; 1.1125x over previous
//
#include <hip/hip_runtime.h>
#include <math.h>

// Problem constants (fixed by the reference)
constexpr int NG    = 128;          // graphs
constexpr int NP    = 1024;         // nodes per graph
constexpr int D     = 256;          // feature dim
constexpr int NTOT  = NG * NP;      // 131072 nodes
constexpr int EPG   = NP * 32;      // 32768 edges per graph (contiguous slice)
constexpr int ET    = NTOT * 32;    // 4194304 edges
constexpr int KK    = 820;          // kept per graph
constexpr int NKEEP = NG * KK;      // 104960 kept nodes
constexpr int BPG   = 4;            // edge slices per graph (K3 edge remap)
constexpr int EPB   = EPG / BPG;    // 8192 edges per slice
constexpr int NBE   = NG * BPG;     // 512 edge slices total

// Grid geometry
constexpr int K1_DEG    = NG;               // blocks 0..127: per-graph degree
constexpr int K1_HBLK   = 2048;             // h blocks (64 rows each)
constexpr int K1_BLOCKS = K1_DEG + K1_HBLK; // 2176
constexpr int K3_BLOCKS = 2048;             // 512 edge + 1536 gather blocks

// Native clang vector type: __builtin_nontemporal_store rejects HIP float4
typedef float v4f __attribute__((ext_vector_type(4)));

// Output layout (flat float32, reference return order)
constexpr long long OUT_X     = 0;
constexpr long long OUT_EI0   = (long long)NKEEP * D;     // 26869760
constexpr long long OUT_EI1   = OUT_EI0 + ET;
constexpr long long OUT_MASK  = OUT_EI0 + 2LL * ET;
constexpr long long OUT_BATCH = OUT_MASK + ET;
constexpr long long OUT_PERM  = OUT_BATCH + NKEEP;        // total 39662592

// ---------------------------------------------------------------------------
// K1: co-running roles (deg hides under the 134 MB h-stream).
//   blocks 0..127     : per-graph degree via LDS counters -> dinv[g*NP+i]
//   blocks 128..2175  : h = x@W, wave-per-row float4 unroll-4 (proven R2 form)
__global__ __launch_bounds__(256) void k1_h_deg(const float* __restrict__ x,
                                                const float* __restrict__ W,
                                                const int* __restrict__ cols,
                                                float* __restrict__ h,
                                                float* __restrict__ dinv) {
    __shared__ int cnt[NP];
    const int b = blockIdx.x;
    const int t = threadIdx.x;

    if (b < K1_DEG) {
        const int g = b;
        for (int i = t; i < NP; i += 256) cnt[i] = 0;
        __syncthreads();
        const int4* c4 = (const int4*)(cols + (size_t)g * EPG);
#pragma unroll
        for (int i = t; i < EPG / 4; i += 256) {     // 32 iters
            int4 c = c4[i];
            atomicAdd(&cnt[c.x & (NP - 1)], 1);
            atomicAdd(&cnt[c.y & (NP - 1)], 1);
            atomicAdd(&cnt[c.z & (NP - 1)], 1);
            atomicAdd(&cnt[c.w & (NP - 1)], 1);
        }
        __syncthreads();
        for (int i = t; i < NP; i += 256)
            dinv[g * NP + i] = rsqrtf((float)(1 + cnt[i]));  // self-loop incl.
        return;
    }

    // h pass: wave-per-row, 16 consecutive rows per wave, 4 in flight
    const int bb   = b - K1_DEG;
    const int w    = t >> 6;
    const int lane = t & 63;
    const int gw   = bb * 4 + w;                     // 0..8191
    float4 w4 = ((const float4*)W)[lane];
    const float4* xp = (const float4*)(x + (size_t)gw * 16 * D);
#pragma unroll
    for (int c = 0; c < 4; ++c) {
        float4 a0 = xp[(c * 4 + 0) * 64 + lane];
        float4 a1 = xp[(c * 4 + 1) * 64 + lane];
        float4 a2 = xp[(c * 4 + 2) * 64 + lane];
        float4 a3 = xp[(c * 4 + 3) * 64 + lane];
        float s0 = a0.x * w4.x + a0.y * w4.y + a0.z * w4.z + a0.w * w4.w;
        float s1 = a1.x * w4.x + a1.y * w4.y + a1.z * w4.z + a1.w * w4.w;
        float s2 = a2.x * w4.x + a2.y * w4.y + a2.z * w4.z + a2.w * w4.w;
        float s3 = a3.x * w4.x + a3.y * w4.y + a3.z * w4.z + a3.w * w4.w;
#pragma unroll
        for (int off = 32; off > 0; off >>= 1) {     // 4 interleaved chains
            s0 += __shfl_down(s0, off, 64);
            s1 += __shfl_down(s1, off, 64);
            s2 += __shfl_down(s2, off, 64);
            s3 += __shfl_down(s3, off, 64);
        }
        if (lane == 0) {
            const int r = gw * 16 + c * 4;
            h[r] = s0; h[r + 1] = s1; h[r + 2] = s2; h[r + 3] = s3;
        }
    }
}

// ---------------------------------------------------------------------------
// K2: one 1024-thread block per graph, done ONCE (round 7 paid this 4x):
//     ul = dinv*h -> acc[c] += ul[r] (LDS atomics) -> score -> register
//     bitonic full sort -> write new_id for ALL nodes (rank t writes the
//     node at rank t: a permutation covers every node, so no -1 init pass),
//     plus perm_i/factor/out_perm/out_batch.
//     LDS: sk 8KB (low half aliases ul) + acc 4KB + scl 4KB = 16 KB.
__global__ __launch_bounds__(1024) void k2_graph(
        const float* __restrict__ h,    const float* __restrict__ dinv,
        const float* __restrict__ bptr,
        const int* __restrict__ rows,   const int* __restrict__ cols,
        int* __restrict__ perm_i,       float* __restrict__ factor,
        int* __restrict__ new_id,
        float* __restrict__ out_perm,   float* __restrict__ out_batch) {
    __shared__ unsigned long long sk[NP];   // sort buffer; low 4KB aliases ul
    __shared__ float acc[NP];
    __shared__ float scl[NP];
    float* ul = (float*)sk;                 // dead before first sort LDS stage

    const int g = blockIdx.x;
    const int t = threadIdx.x;

    const float hv = h[g * NP + t];
    const float dv = dinv[g * NP + t];
    ul[t]  = dv * hv;
    acc[t] = 0.0f;
    __syncthreads();

    const int4* c4 = (const int4*)(cols + (size_t)g * EPG);
    const int4* r4 = (const int4*)(rows + (size_t)g * EPG);
#pragma unroll
    for (int i = t; i < EPG / 4; i += 1024) {        // 8 iters
        int4 c = c4[i];
        int4 r = r4[i];
        atomicAdd(&acc[c.x & (NP - 1)], ul[r.x & (NP - 1)]);
        atomicAdd(&acc[c.y & (NP - 1)], ul[r.y & (NP - 1)]);
        atomicAdd(&acc[c.z & (NP - 1)], ul[r.z & (NP - 1)]);
        atomicAdd(&acc[c.w & (NP - 1)], ul[r.w & (NP - 1)]);
    }
    __syncthreads();
    // all ul reads complete at this barrier -> sk is free for the sort

    const float score = dv * acc[t] + dv * dv * hv + bptr[0];
    scl[t] = score;

    // sortable key: ascending u64 == (descending score, ascending idx)
    unsigned int fu = __float_as_uint(score);
    unsigned int s  = (fu & 0x80000000u) ? ~fu : (fu | 0x80000000u);
    unsigned long long key = ((unsigned long long)(~s) << 32) | (unsigned int)t;

    for (int k = 2; k <= NP; k <<= 1) {
        for (int j = k >> 1; j > 0; j >>= 1) {
            unsigned long long other;
            if (j < 64) {
                other = __shfl_xor(key, j, 64);
            } else {
                sk[t] = key;
                __syncthreads();
                other = sk[t ^ j];
                __syncthreads();
            }
            bool take_min = (((t & k) == 0) == ((t & j) == 0));
            bool omin = other < key;
            key = (take_min == omin) ? other : key;
        }
    }
    // sort's internal barriers ordered scl[] writes before the reads below

    const int idx = (int)(key & 0xFFFFFFFFull);      // node at rank t
    if (t < KK) {
        const int jj = g * KK + t;
        new_id[g * NP + idx] = jj;
        perm_i[jj]   = g * NP + idx;
        factor[jj]   = tanhf(scl[idx]);
        out_perm[jj]  = (float)(g * NP + idx);
        out_batch[jj] = (float)g;        // graphs contiguous: batch[node] == g
    } else {
        new_id[g * NP + idx] = -1;       // dropped node; permutation covers all
    }
}

// ---------------------------------------------------------------------------
// K3: gather + edge remap, disjoint block roles (proven R2 structure).
//     Blocks 0..511: remap one 8192-edge slice (new_id slice staged in LDS).
//     Blocks 512..2047: wave-per-row gather over NKEEP rows.
//     Nontemporal output stores keep x resident in L3 for the gather.
__global__ __launch_bounds__(256) void k3_gather_edge(
        const float* __restrict__ x,
        const int* __restrict__ rows, const int* __restrict__ cols,
        const int* __restrict__ new_id,
        const int* __restrict__ perm_i, const float* __restrict__ factor,
        float* __restrict__ out) {
    __shared__ int nid[NP];
    const int b    = blockIdx.x;
    const int t    = threadIdx.x;
    const int w    = t >> 6;
    const int lane = t & 63;

    if (b < NBE) {
        const int g = b >> 2;
        for (int i = t; i < NP; i += 256) nid[i] = new_id[g * NP + i];
        __syncthreads();
        size_t eoff = (size_t)g * EPG + (size_t)(b & 3) * EPB;
        const int4* r4 = (const int4*)(rows + eoff);
        const int4* c4 = (const int4*)(cols + eoff);
        v4f* orr = (v4f*)(out + OUT_EI0  + eoff);
        v4f* occ = (v4f*)(out + OUT_EI1  + eoff);
        v4f* omm = (v4f*)(out + OUT_MASK + eoff);
#pragma unroll
        for (int i = t; i < EPB / 4; i += 256) {   // 8 iters
            int4 r = r4[i];
            int4 c = c4[i];
            v4f fr, fc, fm;
            {
                int nr = nid[r.x & (NP - 1)], nc = nid[c.x & (NP - 1)];
                bool m = (nr >= 0) && (nc >= 0);
                fr.x = m ? (float)nr : -1.0f; fc.x = m ? (float)nc : -1.0f; fm.x = m ? 1.0f : 0.0f;
            }
            {
                int nr = nid[r.y & (NP - 1)], nc = nid[c.y & (NP - 1)];
                bool m = (nr >= 0) && (nc >= 0);
                fr.y = m ? (float)nr : -1.0f; fc.y = m ? (float)nc : -1.0f; fm.y = m ? 1.0f : 0.0f;
            }
            {
                int nr = nid[r.z & (NP - 1)], nc = nid[c.z & (NP - 1)];
                bool m = (nr >= 0) && (nc >= 0);
                fr.z = m ? (float)nr : -1.0f; fc.z = m ? (float)nc : -1.0f; fm.z = m ? 1.0f : 0.0f;
            }
            {
                int nr = nid[r.w & (NP - 1)], nc = nid[c.w & (NP - 1)];
                bool m = (nr >= 0) && (nc >= 0);
                fr.w = m ? (float)nr : -1.0f; fc.w = m ? (float)nc : -1.0f; fm.w = m ? 1.0f : 0.0f;
            }
            __builtin_nontemporal_store(fr, &orr[i]);
            __builtin_nontemporal_store(fc, &occ[i]);
            __builtin_nontemporal_store(fm, &omm[i]);
        }
    } else {
        // gather: x_new[j,:] = x[perm[j],:] * factor[j]; wave-per-row
        const int gw = (b - NBE) * 4 + w;              // 0..6143
        for (int j = gw; j < NKEEP; j += (K3_BLOCKS - NBE) * 4) {   // 17-18 it
            const int node = perm_i[j];
            const float f  = factor[j];
            float4 v = ((const float4*)(x + (size_t)node * D))[lane];
            v4f o;
            o.x = v.x * f; o.y = v.y * f; o.z = v.z * f; o.w = v.w * f;
            __builtin_nontemporal_store(o, &((v4f*)(out + OUT_X + (size_t)j * D))[lane]);
        }
    }
}

extern "C" void kernel_launch(void* const* d_in, const int* in_sizes, int n_in,
                              void* d_out, int out_size, void* d_ws, size_t ws_size,
                              hipStream_t stream) {
    (void)in_sizes; (void)n_in; (void)out_size; (void)ws_size;

    const float* x  = (const float*)d_in[0];
    const int*   ei = (const int*)d_in[1];
    // d_in[2] (batch) unused: graphs are contiguous so batch[node] = node/NP
    const float* W  = (const float*)d_in[3];
    const float* b  = (const float*)d_in[4];
    float* out = (float*)d_out;

    // Workspace layout (~2.4 MB; ws is poisoned each call -> all re-inited)
    float* wsf      = (float*)d_ws;
    float* h        = wsf;                                // [NTOT]
    float* dinv     = wsf + NTOT;                         // [NTOT]
    int*   new_id   = (int*)(wsf + 2 * NTOT);             // [NTOT]
    int*   perm_i   = (int*)(wsf + 3 * NTOT);             // [NKEEP]
    float* factor   = wsf + 3 * NTOT + NKEEP;             // [NKEEP]

    const int* rows = ei;        // edge_index[0] = sources
    const int* cols = ei + ET;   // edge_index[1] = targets

    hipLaunchKernelGGL(k1_h_deg, dim3(K1_BLOCKS), dim3(256), 0, stream,
                       x, W, cols, h, dinv);
    hipLaunchKernelGGL(k2_graph, dim3(NG), dim3(1024), 0, stream,
                       h, dinv, b, rows, cols, perm_i, factor, new_id,
                       out + OUT_PERM, out + OUT_BATCH);
    hipLaunchKernelGGL(k3_gather_edge, dim3(K3_BLOCKS), dim3(256), 0, stream,
                       x, rows, cols, new_id, perm_i, factor, out);
}